// Round 4
// baseline (16.372 us; speedup 1.0000x reference)
//
#include <hip/hip_runtime.h>

#define NROWS 4096
#define DCOLS 512
#define NBLK  256                      // K1 blocks
#define ROWS_PER_BLOCK (NROWS / NBLK)  // 16
#define RBLK  64                       // K2 blocks (8 columns each)
#define EPSF 1e-8f

// ---------------------------------------------------------------------------
// K1: 256 blocks x 512 threads (8 waves). One wave per row, 2 rows/wave.
// Lane l owns columns {4l..4l+3} and {256+4l..256+4l+3} (two float4).
// Per row: wave butterfly reduce (x.x, y.y, x.y), normalize, accumulate
// per-column partials. Block epilogue combines 8 waves via LDS and writes
// TRANSPOSED partials part[col*NBLK + blk] so K2 reads coalesced.
// Block 0 also resets K2's ticket counter (kernel boundary makes it visible).
// ---------------------------------------------------------------------------
__global__ __launch_bounds__(512) void cosloss_main(const float4* __restrict__ x4,
                                                    const float4* __restrict__ y4,
                                                    float* __restrict__ partx,
                                                    float* __restrict__ party,
                                                    float* __restrict__ partd,
                                                    unsigned* __restrict__ ticket) {
    __shared__ float4 smem[8][128];   // 16 KB, reused for x then y
    __shared__ float ldsd[8];

    const int t    = threadIdx.x;
    const int lane = t & 63;
    const int wave = t >> 6;
    const int row0 = blockIdx.x * ROWS_PER_BLOCK + wave * 2;

    if (blockIdx.x == 0 && t == 0) *ticket = 0u;   // robust re-init every call

    float4 psx0 = {0.f,0.f,0.f,0.f}, psx1 = {0.f,0.f,0.f,0.f};
    float4 psy0 = {0.f,0.f,0.f,0.f}, psy1 = {0.f,0.f,0.f,0.f};
    float pdiag = 0.f;

    #pragma unroll
    for (int r = 0; r < 2; ++r) {
        const size_t base = (size_t)(row0 + r) * (DCOLS / 4) + lane;
        const float4 x0 = x4[base];
        const float4 x1 = x4[base + 64];
        const float4 y0 = y4[base];
        const float4 y1 = y4[base + 64];

        float sxx = x0.x*x0.x + x0.y*x0.y + x0.z*x0.z + x0.w*x0.w
                  + x1.x*x1.x + x1.y*x1.y + x1.z*x1.z + x1.w*x1.w;
        float syy = y0.x*y0.x + y0.y*y0.y + y0.z*y0.z + y0.w*y0.w
                  + y1.x*y1.x + y1.y*y1.y + y1.z*y1.z + y1.w*y1.w;
        float sxy = x0.x*y0.x + x0.y*y0.y + x0.z*y0.z + x0.w*y0.w
                  + x1.x*y1.x + x1.y*y1.y + x1.z*y1.z + x1.w*y1.w;

        #pragma unroll
        for (int off = 1; off < 64; off <<= 1) {
            sxx += __shfl_xor(sxx, off, 64);
            syy += __shfl_xor(syy, off, 64);
            sxy += __shfl_xor(sxy, off, 64);
        }

        const float inx = 1.0f / fmaxf(sqrtf(sxx), EPSF);
        const float iny = 1.0f / fmaxf(sqrtf(syy), EPSF);

        psx0.x += x0.x*inx; psx0.y += x0.y*inx; psx0.z += x0.z*inx; psx0.w += x0.w*inx;
        psx1.x += x1.x*inx; psx1.y += x1.y*inx; psx1.z += x1.z*inx; psx1.w += x1.w*inx;
        psy0.x += y0.x*iny; psy0.y += y0.y*iny; psy0.z += y0.z*iny; psy0.w += y0.w*iny;
        psy1.x += y1.x*iny; psy1.y += y1.y*iny; psy1.z += y1.z*iny; psy1.w += y1.w*iny;
        pdiag += sxy * inx * iny;
    }

    // ---- x column partials ----
    smem[wave][lane]      = psx0;
    smem[wave][64 + lane] = psx1;
    if (lane == 0) ldsd[wave] = pdiag;
    __syncthreads();
    {
        const float* sm = (const float*)smem;
        float s = 0.f;
        #pragma unroll
        for (int w = 0; w < 8; ++w) s += sm[w * 512 + t];
        partx[(size_t)t * NBLK + blockIdx.x] = s;   // transposed
    }
    __syncthreads();

    // ---- y column partials ----
    smem[wave][lane]      = psy0;
    smem[wave][64 + lane] = psy1;
    __syncthreads();
    {
        const float* sm = (const float*)smem;
        float s = 0.f;
        #pragma unroll
        for (int w = 0; w < 8; ++w) s += sm[w * 512 + t];
        party[(size_t)t * NBLK + blockIdx.x] = s;   // transposed
    }

    if (t == 0) {
        float d = 0.f;
        #pragma unroll
        for (int w = 0; w < 8; ++w) d += ldsd[w];
        partd[blockIdx.x] = d;
    }
}

// ---------------------------------------------------------------------------
// K2: 64 blocks x 512 threads. Wave w of block b owns column c = b*8 + w.
// Lane l loads float4 of the 256 cross-block partials (coalesced), shuffle
// reduce -> colprod. Block folds its 8 colprods minus its 4 diag partials
// into one fp32 scalar, publishes it, takes a ticket; the last block
// acquire-loads all 64 scalars with one wave and writes the final result.
// ---------------------------------------------------------------------------
__global__ __launch_bounds__(512) void cosloss_reduce(const float* __restrict__ partx,
                                                      const float* __restrict__ party,
                                                      const float* __restrict__ partd,
                                                      float* __restrict__ blockpart,
                                                      unsigned* __restrict__ ticket,
                                                      float* __restrict__ out) {
    __shared__ float ldsc[8];
    __shared__ unsigned flag;
    const int t    = threadIdx.x;
    const int lane = t & 63;
    const int wave = t >> 6;
    const int c    = blockIdx.x * 8 + wave;

    const float4* bx4 = (const float4*)(partx + (size_t)c * NBLK);
    const float4* by4 = (const float4*)(party + (size_t)c * NBLK);
    const float4 xv = bx4[lane];
    const float4 yv = by4[lane];
    float sx = xv.x + xv.y + xv.z + xv.w;
    float sy = yv.x + yv.y + yv.z + yv.w;

    #pragma unroll
    for (int off = 32; off > 0; off >>= 1) {
        sx += __shfl_down(sx, off, 64);
        sy += __shfl_down(sy, off, 64);
    }
    if (lane == 0) ldsc[wave] = sx * sy;
    __syncthreads();

    if (t == 0) {
        float v = 0.f;
        #pragma unroll
        for (int w = 0; w < 8; ++w) v += ldsc[w];
        #pragma unroll
        for (int i = 0; i < 4; ++i) v -= partd[blockIdx.x * 4 + i];
        blockpart[blockIdx.x] = v;
        __threadfence();
        const unsigned old = __hip_atomic_fetch_add(ticket, 1u, __ATOMIC_ACQ_REL,
                                                    __HIP_MEMORY_SCOPE_AGENT);
        flag = (old == RBLK - 1) ? 1u : 0u;
    }
    __syncthreads();

    if (flag && wave == 0) {
        float v = __hip_atomic_load(&blockpart[lane], __ATOMIC_ACQUIRE,
                                    __HIP_MEMORY_SCOPE_AGENT);
        #pragma unroll
        for (int off = 32; off > 0; off >>= 1) v += __shfl_down(v, off, 64);
        if (lane == 0) out[0] = v / 16777216.0f;   // / 4096^2 (exact pow2 scale)
    }
}

extern "C" void kernel_launch(void* const* d_in, const int* in_sizes, int n_in,
                              void* d_out, int out_size, void* d_ws, size_t ws_size,
                              hipStream_t stream) {
    const float4* x4 = (const float4*)d_in[0];
    const float4* y4 = (const float4*)d_in[1];
    float* out = (float*)d_out;

    float* partx     = (float*)d_ws;                   // 512*256 floats
    float* party     = partx + (size_t)DCOLS * NBLK;   // 512*256 floats
    float* partd     = party + (size_t)DCOLS * NBLK;   // 256 floats
    float* blockpart = partd + NBLK;                   // 64 floats
    unsigned* ticket = (unsigned*)(blockpart + RBLK);  // 1 uint

    cosloss_main<<<NBLK, 512, 0, stream>>>(x4, y4, partx, party, partd, ticket);
    cosloss_reduce<<<RBLK, 512, 0, stream>>>(partx, party, partd, blockpart, ticket, out);
}